// Round 1
// baseline (1041.244 us; speedup 1.0000x reference)
//
#include <hip/hip_runtime.h>

#define NB 4
#define NS 2048
#define ND 512
#define NH 8
#define NDK 64
#define LN_EPS 1e-5f

// ---------------------------------------------------------------------------
// Projection GEMM: C[r][c] = sum_k X[r][k] * W[c][k] + bias[c]
// X: [NB*NS, ND], W: [ND, ND] (row-major [out,in]).
// Output written in [B, H, S, DK] layout for attention.
// 64x64 tile, BK=16, 256 threads, 4x4 micro-tile.
// ---------------------------------------------------------------------------
__global__ __launch_bounds__(256) void k_proj(
    const float* __restrict__ X, const float* __restrict__ W,
    const float* __restrict__ bias, float* __restrict__ out)
{
    __shared__ float As[16][68];   // [k][row], pad 68 keeps 16B alignment
    __shared__ float Bs[16][68];   // [k][col]
    const int tid = threadIdx.x;
    const int tx = tid & 15, ty = tid >> 4;
    const int row0 = blockIdx.y * 64;
    const int col0 = blockIdx.x * 64;
    const int lk = tid & 15;       // k within tile
    const int lr = tid >> 4;       // row group

    float acc[4][4] = {};

    for (int k0 = 0; k0 < ND; k0 += 16) {
#pragma unroll
        for (int i = 0; i < 4; ++i) {
            As[lk][lr + 16 * i] = X[(size_t)(row0 + lr + 16 * i) * ND + k0 + lk];
            Bs[lk][lr + 16 * i] = W[(size_t)(col0 + lr + 16 * i) * ND + k0 + lk];
        }
        __syncthreads();
#pragma unroll
        for (int kk = 0; kk < 16; ++kk) {
            float a[4], b[4];
#pragma unroll
            for (int i = 0; i < 4; ++i) a[i] = As[kk][ty * 4 + i];
#pragma unroll
            for (int j = 0; j < 4; ++j) b[j] = Bs[kk][tx * 4 + j];
#pragma unroll
            for (int i = 0; i < 4; ++i)
#pragma unroll
                for (int j = 0; j < 4; ++j)
                    acc[i][j] += a[i] * b[j];
        }
        __syncthreads();
    }

#pragma unroll
    for (int i = 0; i < 4; ++i) {
        int r = row0 + ty * 4 + i;
        int b_ = r >> 11;          // r / NS
        int s_ = r & (NS - 1);
#pragma unroll
        for (int j = 0; j < 4; ++j) {
            int c = col0 + tx * 4 + j;
            int h_ = c >> 6;       // c / NDK
            int dk = c & (NDK - 1);
            out[(((size_t)b_ * NH + h_) * NS + s_) * NDK + dk] = acc[i][j] + bias[c];
        }
    }
}

// ---------------------------------------------------------------------------
// scores[bh][row][col] = sum_dk q[bh][row][dk] * k[bh][col][dk]
// K = DK = 64 fits entirely in LDS: single stage, no K loop.
// ---------------------------------------------------------------------------
__global__ __launch_bounds__(256) void k_scores(
    const float* __restrict__ q, const float* __restrict__ k,
    float* __restrict__ attn)
{
    __shared__ float Qs[64][68];   // [dk][row]
    __shared__ float Ks[64][68];   // [dk][col]
    const int tid = threadIdx.x;
    const int tx = tid & 15, ty = tid >> 4;
    const int bh = blockIdx.z;
    const int row0 = blockIdx.y * 64;
    const int col0 = blockIdx.x * 64;
    const float* qb = q + (size_t)bh * NS * NDK;
    const float* kb = k + (size_t)bh * NS * NDK;

    const int r16 = tid >> 4;      // 0..15
    const int c4 = tid & 15;       // float4 group within row of 64
#pragma unroll
    for (int i = 0; i < 4; ++i) {
        int r = r16 + 16 * i;
        float4 a = *(const float4*)&qb[(size_t)(row0 + r) * NDK + c4 * 4];
        Qs[c4 * 4 + 0][r] = a.x; Qs[c4 * 4 + 1][r] = a.y;
        Qs[c4 * 4 + 2][r] = a.z; Qs[c4 * 4 + 3][r] = a.w;
        float4 b = *(const float4*)&kb[(size_t)(col0 + r) * NDK + c4 * 4];
        Ks[c4 * 4 + 0][r] = b.x; Ks[c4 * 4 + 1][r] = b.y;
        Ks[c4 * 4 + 2][r] = b.z; Ks[c4 * 4 + 3][r] = b.w;
    }
    __syncthreads();

    float acc[4][4] = {};
#pragma unroll 16
    for (int kk = 0; kk < 64; ++kk) {
        float a[4], b[4];
#pragma unroll
        for (int i = 0; i < 4; ++i) a[i] = Qs[kk][ty * 4 + i];
#pragma unroll
        for (int j = 0; j < 4; ++j) b[j] = Ks[kk][tx * 4 + j];
#pragma unroll
        for (int i = 0; i < 4; ++i)
#pragma unroll
            for (int j = 0; j < 4; ++j)
                acc[i][j] += a[i] * b[j];
    }

    float* ab = attn + (size_t)bh * NS * NS;
#pragma unroll
    for (int i = 0; i < 4; ++i) {
        float4 o = { acc[i][0], acc[i][1], acc[i][2], acc[i][3] };
        *(float4*)&ab[(size_t)(row0 + ty * 4 + i) * NS + col0 + tx * 4] = o;
    }
}

// ---------------------------------------------------------------------------
// In-place row softmax over NS=2048. One block per row; 8 f32 per thread
// held in registers: single global read + write.
// ---------------------------------------------------------------------------
__global__ __launch_bounds__(256) void k_softmax(float* __restrict__ attn)
{
    const int tid = threadIdx.x;
    float* p = attn + (size_t)blockIdx.x * NS;
    float4 v0 = *(const float4*)&p[tid * 4];
    float4 v1 = *(const float4*)&p[1024 + tid * 4];

    float m = fmaxf(fmaxf(fmaxf(v0.x, v0.y), fmaxf(v0.z, v0.w)),
                    fmaxf(fmaxf(v1.x, v1.y), fmaxf(v1.z, v1.w)));
#pragma unroll
    for (int off = 32; off > 0; off >>= 1) m = fmaxf(m, __shfl_xor(m, off));
    __shared__ float redm[4];
    __shared__ float reds[4];
    if ((tid & 63) == 0) redm[tid >> 6] = m;
    __syncthreads();
    const float M = fmaxf(fmaxf(redm[0], redm[1]), fmaxf(redm[2], redm[3]));

    v0.x = expf(v0.x - M); v0.y = expf(v0.y - M);
    v0.z = expf(v0.z - M); v0.w = expf(v0.w - M);
    v1.x = expf(v1.x - M); v1.y = expf(v1.y - M);
    v1.z = expf(v1.z - M); v1.w = expf(v1.w - M);

    float s = (v0.x + v0.y + v0.z + v0.w) + (v1.x + v1.y + v1.z + v1.w);
#pragma unroll
    for (int off = 32; off > 0; off >>= 1) s += __shfl_xor(s, off);
    if ((tid & 63) == 0) reds[tid >> 6] = s;
    __syncthreads();
    const float inv = 1.0f / (reds[0] + reds[1] + reds[2] + reds[3]);

    v0.x *= inv; v0.y *= inv; v0.z *= inv; v0.w *= inv;
    v1.x *= inv; v1.y *= inv; v1.z *= inv; v1.w *= inv;
    *(float4*)&p[tid * 4] = v0;
    *(float4*)&p[1024 + tid * 4] = v1;
}

// ---------------------------------------------------------------------------
// ctx[b][s][h*64+dk] = sum_k attn[bh][s][k] * v[bh][k][dk]
// 64 rows x 64 cols (full DK) per block, BK=32.
// ---------------------------------------------------------------------------
__global__ __launch_bounds__(256) void k_context(
    const float* __restrict__ attn, const float* __restrict__ v,
    float* __restrict__ ctx)
{
    __shared__ float As[32][68];   // [k][row]
    __shared__ float Vs[32][64];   // [k][col]
    const int tid = threadIdx.x;
    const int tx = tid & 15, ty = tid >> 4;
    const int row0 = blockIdx.x * 64;
    const int bh = blockIdx.y;
    const float* ab = attn + (size_t)bh * NS * NS;
    const float* vb = v + (size_t)bh * NS * NDK;

    float acc[4][4] = {};

    for (int k0 = 0; k0 < NS; k0 += 32) {
#pragma unroll
        for (int i = 0; i < 2; ++i) {
            int r = (tid >> 3) + 32 * i;
            int kg = tid & 7;
            float4 a = *(const float4*)&ab[(size_t)(row0 + r) * NS + k0 + kg * 4];
            As[kg * 4 + 0][r] = a.x; As[kg * 4 + 1][r] = a.y;
            As[kg * 4 + 2][r] = a.z; As[kg * 4 + 3][r] = a.w;
        }
        {
            int kr = tid >> 4;       // 0..15
            int cg = tid & 15;
#pragma unroll
            for (int i = 0; i < 2; ++i) {
                float4 b = *(const float4*)&vb[(size_t)(k0 + kr + 16 * i) * NDK + cg * 4];
                *(float4*)&Vs[kr + 16 * i][cg * 4] = b;
            }
        }
        __syncthreads();
#pragma unroll 8
        for (int kk = 0; kk < 32; ++kk) {
            float a[4], b[4];
#pragma unroll
            for (int i = 0; i < 4; ++i) a[i] = As[kk][ty * 4 + i];
#pragma unroll
            for (int j = 0; j < 4; ++j) b[j] = Vs[kk][tx * 4 + j];
#pragma unroll
            for (int i = 0; i < 4; ++i)
#pragma unroll
                for (int j = 0; j < 4; ++j)
                    acc[i][j] += a[i] * b[j];
        }
        __syncthreads();
    }

    const int b_ = bh >> 3, h_ = bh & 7;
#pragma unroll
    for (int i = 0; i < 4; ++i) {
        int r = row0 + ty * 4 + i;
        float4 o = { acc[i][0], acc[i][1], acc[i][2], acc[i][3] };
        *(float4*)&ctx[((size_t)b_ * NS + r) * ND + h_ * NDK + tx * 4] = o;
    }
}

// ---------------------------------------------------------------------------
// out[r][c] = sum_k ctx[r][k] * Wo[c][k] + bo[c] + residual[r][c]
// ---------------------------------------------------------------------------
__global__ __launch_bounds__(256) void k_outproj(
    const float* __restrict__ Xc, const float* __restrict__ W,
    const float* __restrict__ bias, const float* __restrict__ Qin,
    float* __restrict__ out)
{
    __shared__ float As[16][68];
    __shared__ float Bs[16][68];
    const int tid = threadIdx.x;
    const int tx = tid & 15, ty = tid >> 4;
    const int row0 = blockIdx.y * 64;
    const int col0 = blockIdx.x * 64;
    const int lk = tid & 15;
    const int lr = tid >> 4;

    float acc[4][4] = {};

    for (int k0 = 0; k0 < ND; k0 += 16) {
#pragma unroll
        for (int i = 0; i < 4; ++i) {
            As[lk][lr + 16 * i] = Xc[(size_t)(row0 + lr + 16 * i) * ND + k0 + lk];
            Bs[lk][lr + 16 * i] = W[(size_t)(col0 + lr + 16 * i) * ND + k0 + lk];
        }
        __syncthreads();
#pragma unroll
        for (int kk = 0; kk < 16; ++kk) {
            float a[4], b[4];
#pragma unroll
            for (int i = 0; i < 4; ++i) a[i] = As[kk][ty * 4 + i];
#pragma unroll
            for (int j = 0; j < 4; ++j) b[j] = Bs[kk][tx * 4 + j];
#pragma unroll
            for (int i = 0; i < 4; ++i)
#pragma unroll
                for (int j = 0; j < 4; ++j)
                    acc[i][j] += a[i] * b[j];
        }
        __syncthreads();
    }

#pragma unroll
    for (int i = 0; i < 4; ++i) {
        int r = row0 + ty * 4 + i;
        int c = col0 + tx * 4;
        float4 res = *(const float4*)&Qin[(size_t)r * ND + c];
        float4 o;
        o.x = acc[i][0] + bias[c + 0] + res.x;
        o.y = acc[i][1] + bias[c + 1] + res.y;
        o.z = acc[i][2] + bias[c + 2] + res.z;
        o.w = acc[i][3] + bias[c + 3] + res.w;
        *(float4*)&out[(size_t)r * ND + c] = o;
    }
}

// ---------------------------------------------------------------------------
// In-place LayerNorm over last dim (512). One block per row, 2 f32/thread.
// ---------------------------------------------------------------------------
__global__ __launch_bounds__(256) void k_ln(
    float* __restrict__ out, const float* __restrict__ gamma,
    const float* __restrict__ beta)
{
    const int tid = threadIdx.x;
    float* p = out + (size_t)blockIdx.x * ND;
    float2 v = *(const float2*)&p[tid * 2];

    float s = v.x + v.y;
#pragma unroll
    for (int off = 32; off > 0; off >>= 1) s += __shfl_xor(s, off);
    __shared__ float red1[4];
    __shared__ float red2[4];
    if ((tid & 63) == 0) red1[tid >> 6] = s;
    __syncthreads();
    const float mu = (red1[0] + red1[1] + red1[2] + red1[3]) * (1.0f / ND);

    float dx = v.x - mu, dy = v.y - mu;
    float q = dx * dx + dy * dy;
#pragma unroll
    for (int off = 32; off > 0; off >>= 1) q += __shfl_xor(q, off);
    if ((tid & 63) == 0) red2[tid >> 6] = q;
    __syncthreads();
    const float var = (red2[0] + red2[1] + red2[2] + red2[3]) * (1.0f / ND);
    const float inv = rsqrtf(var + LN_EPS);

    float2 g = *(const float2*)&gamma[tid * 2];
    float2 be = *(const float2*)&beta[tid * 2];
    float2 o = { dx * inv * g.x + be.x, dy * inv * g.y + be.y };
    *(float2*)&p[tid * 2] = o;
}

// ---------------------------------------------------------------------------
extern "C" void kernel_launch(void* const* d_in, const int* in_sizes, int n_in,
                              void* d_out, int out_size, void* d_ws, size_t ws_size,
                              hipStream_t stream)
{
    const float* Q    = (const float*)d_in[0];
    const float* K    = (const float*)d_in[1];
    const float* V    = (const float*)d_in[2];
    const float* Wq   = (const float*)d_in[3];
    const float* bq   = (const float*)d_in[4];
    const float* Wk   = (const float*)d_in[5];
    const float* bk   = (const float*)d_in[6];
    const float* Wv   = (const float*)d_in[7];
    const float* bv   = (const float*)d_in[8];
    const float* Wo   = (const float*)d_in[9];
    const float* bo   = (const float*)d_in[10];
    const float* gam  = (const float*)d_in[11];
    const float* bet  = (const float*)d_in[12];

    float* out  = (float*)d_out;                       // [NB*NS*ND]
    float* attn = out + (size_t)NB * NS * ND;          // [NB*NH*NS*NS]

    const size_t qkv_elems = (size_t)NB * NH * NS * NDK;
    float* qw = (float*)d_ws;
    float* kw = qw + qkv_elems;
    float* vw = kw + qkv_elems;
    float* ctx = qw;   // q dead after k_scores; reuse its region for context

    dim3 blk(256);

    dim3 gProj(ND / 64, (NB * NS) / 64);               // (8, 128)
    k_proj<<<gProj, blk, 0, stream>>>(Q, Wq, bq, qw);
    k_proj<<<gProj, blk, 0, stream>>>(K, Wk, bk, kw);
    k_proj<<<gProj, blk, 0, stream>>>(V, Wv, bv, vw);

    dim3 gSc(NS / 64, NS / 64, NB * NH);               // (32, 32, 32)
    k_scores<<<gSc, blk, 0, stream>>>(qw, kw, attn);

    k_softmax<<<dim3(NB * NH * NS), blk, 0, stream>>>(attn);

    dim3 gCtx(NS / 64, NB * NH);                       // (32, 32)
    k_context<<<gCtx, blk, 0, stream>>>(attn, vw, ctx);

    dim3 gOut(ND / 64, (NB * NS) / 64);
    k_outproj<<<gOut, blk, 0, stream>>>(ctx, Wo, bo, Q, out);

    k_ln<<<dim3(NB * NS), blk, 0, stream>>>(out, gam, bet);
}

// Round 2
// 993.750 us; speedup vs baseline: 1.0478x; 1.0478x over previous
//
#include <hip/hip_runtime.h>

#define NB 4
#define NS 2048
#define ND 512
#define NH 8
#define NDK 64
#define LN_EPS 1e-5f

// ---------------------------------------------------------------------------
// Projection GEMM: C[r][c] = sum_k X[r][k] * W[c][k] + bias[c]
// X: [NB*NS, ND], W: [ND, ND] row-major [out,in]. Output -> [B,H,S,DK].
// 128x128 tile, BK=32, 256 threads, 8x8 micro-tile.
// ---------------------------------------------------------------------------
__global__ __launch_bounds__(256) void k_proj(
    const float* __restrict__ X, const float* __restrict__ W,
    const float* __restrict__ bias, float* __restrict__ out)
{
    __shared__ float As[32][132];   // [k][row]
    __shared__ float Bs[32][132];   // [k][col]
    const int tid = threadIdx.x;
    const int tx = tid & 15, ty = tid >> 4;
    const int row0 = blockIdx.y * 128;
    const int col0 = blockIdx.x * 128;
    const int sr = tid >> 3;        // 0..31
    const int sc = tid & 7;         // float4 group in 32-wide K slab

    float acc[8][8] = {};

    for (int k0 = 0; k0 < ND; k0 += 32) {
#pragma unroll
        for (int i = 0; i < 4; ++i) {
            int r = sr + 32 * i;
            float4 a = *(const float4*)&X[(size_t)(row0 + r) * ND + k0 + sc * 4];
            As[sc*4+0][r]=a.x; As[sc*4+1][r]=a.y; As[sc*4+2][r]=a.z; As[sc*4+3][r]=a.w;
            float4 b = *(const float4*)&W[(size_t)(col0 + r) * ND + k0 + sc * 4];
            Bs[sc*4+0][r]=b.x; Bs[sc*4+1][r]=b.y; Bs[sc*4+2][r]=b.z; Bs[sc*4+3][r]=b.w;
        }
        __syncthreads();
#pragma unroll
        for (int kk = 0; kk < 32; ++kk) {
            float a[8], b[8];
#pragma unroll
            for (int i = 0; i < 8; ++i) a[i] = As[kk][ty * 8 + i];
#pragma unroll
            for (int j = 0; j < 8; ++j) b[j] = Bs[kk][tx * 8 + j];
#pragma unroll
            for (int i = 0; i < 8; ++i)
#pragma unroll
                for (int j = 0; j < 8; ++j)
                    acc[i][j] += a[i] * b[j];
        }
        __syncthreads();
    }

#pragma unroll
    for (int i = 0; i < 8; ++i) {
        int r = row0 + ty * 8 + i;
        int b_ = r >> 11;
        int s_ = r & (NS - 1);
#pragma unroll
        for (int jj = 0; jj < 2; ++jj) {
            int c = col0 + tx * 8 + jj * 4;
            int h_ = c >> 6, dk = c & (NDK - 1);
            float4 o = { acc[i][jj*4+0] + bias[c+0], acc[i][jj*4+1] + bias[c+1],
                         acc[i][jj*4+2] + bias[c+2], acc[i][jj*4+3] + bias[c+3] };
            *(float4*)&out[(((size_t)b_ * NH + h_) * NS + s_) * NDK + dk] = o;
        }
    }
}

// ---------------------------------------------------------------------------
// scores[bh][row][col] = sum_dk q[row][dk]*k[col][dk]; writes RAW scores and
// per-(row, 128-col-block) partial softmax stats (max, sumexp).
// 128x128 tile, K=DK=64 staged in two 32-slabs, 8x8 micro.
// ---------------------------------------------------------------------------
__global__ __launch_bounds__(256) void k_scores(
    const float* __restrict__ q, const float* __restrict__ k,
    float* __restrict__ attn, float* __restrict__ mpart,
    float* __restrict__ lpart)
{
    __shared__ float Qs[32][132];
    __shared__ float Ks[32][132];
    const int tid = threadIdx.x;
    const int tx = tid & 15, ty = tid >> 4;
    const int bh = blockIdx.z;
    const int row0 = blockIdx.y * 128;
    const int col0 = blockIdx.x * 128;
    const float* qb = q + (size_t)bh * NS * NDK;
    const float* kb = k + (size_t)bh * NS * NDK;
    const int sr = tid >> 3;
    const int sc = tid & 7;

    float acc[8][8] = {};

    for (int k0 = 0; k0 < NDK; k0 += 32) {
#pragma unroll
        for (int i = 0; i < 4; ++i) {
            int r = sr + 32 * i;
            float4 a = *(const float4*)&qb[(size_t)(row0 + r) * NDK + k0 + sc * 4];
            Qs[sc*4+0][r]=a.x; Qs[sc*4+1][r]=a.y; Qs[sc*4+2][r]=a.z; Qs[sc*4+3][r]=a.w;
            float4 b = *(const float4*)&kb[(size_t)(col0 + r) * NDK + k0 + sc * 4];
            Ks[sc*4+0][r]=b.x; Ks[sc*4+1][r]=b.y; Ks[sc*4+2][r]=b.z; Ks[sc*4+3][r]=b.w;
        }
        __syncthreads();
#pragma unroll
        for (int kk = 0; kk < 32; ++kk) {
            float a[8], b[8];
#pragma unroll
            for (int i = 0; i < 8; ++i) a[i] = Qs[kk][ty * 8 + i];
#pragma unroll
            for (int j = 0; j < 8; ++j) b[j] = Ks[kk][tx * 8 + j];
#pragma unroll
            for (int i = 0; i < 8; ++i)
#pragma unroll
                for (int j = 0; j < 8; ++j)
                    acc[i][j] += a[i] * b[j];
        }
        __syncthreads();
    }

    float* ab = attn + (size_t)bh * NS * NS;
    const size_t statbase = ((size_t)bh * 16 + blockIdx.x) * NS;
#pragma unroll
    for (int i = 0; i < 8; ++i) {
        int r = row0 + ty * 8 + i;
        float4 o0 = { acc[i][0], acc[i][1], acc[i][2], acc[i][3] };
        float4 o1 = { acc[i][4], acc[i][5], acc[i][6], acc[i][7] };
        *(float4*)&ab[(size_t)r * NS + col0 + tx * 8]     = o0;
        *(float4*)&ab[(size_t)r * NS + col0 + tx * 8 + 4] = o1;

        float m = fmaxf(fmaxf(fmaxf(acc[i][0], acc[i][1]), fmaxf(acc[i][2], acc[i][3])),
                        fmaxf(fmaxf(acc[i][4], acc[i][5]), fmaxf(acc[i][6], acc[i][7])));
#pragma unroll
        for (int off = 1; off < 16; off <<= 1) m = fmaxf(m, __shfl_xor(m, off));
        float l = 0.f;
#pragma unroll
        for (int j = 0; j < 8; ++j) l += expf(acc[i][j] - m);
#pragma unroll
        for (int off = 1; off < 16; off <<= 1) l += __shfl_xor(l, off);
        if (tx == 0) {
            mpart[statbase + r] = m;
            lpart[statbase + r] = l;
        }
    }
}

// ---------------------------------------------------------------------------
// Combine 16 col-block partials per row -> per-row global max M and 1/L.
// ---------------------------------------------------------------------------
__global__ __launch_bounds__(256) void k_redstats(
    const float* __restrict__ mpart, const float* __restrict__ lpart,
    float* __restrict__ Mrow, float* __restrict__ iLrow)
{
    const int idx = blockIdx.x * 256 + threadIdx.x;   // bh*NS + r
    const int bh = idx >> 11, r = idx & (NS - 1);
    const float* mp = mpart + (size_t)bh * 16 * NS + r;
    const float* lp = lpart + (size_t)bh * 16 * NS + r;
    float M = -3.4e38f;
#pragma unroll
    for (int c = 0; c < 16; ++c) M = fmaxf(M, mp[(size_t)c * NS]);
    float L = 0.f;
#pragma unroll
    for (int c = 0; c < 16; ++c) L += lp[(size_t)c * NS] * expf(mp[(size_t)c * NS] - M);
    Mrow[idx] = M;
    iLrow[idx] = 1.0f / L;
}

// ---------------------------------------------------------------------------
// Normalize + PV in one pass: reads raw scores, p = exp(s-M)*iL, writes p
// back to attn (final output) and computes ctx = p @ V.
// 128 rows x 64 cols (full DK), BK=32, 8x4 micro.
// ---------------------------------------------------------------------------
__global__ __launch_bounds__(256) void k_ctx(
    const float* __restrict__ v, float* __restrict__ attn,
    const float* __restrict__ Mrow, const float* __restrict__ iLrow,
    float* __restrict__ ctx)
{
    __shared__ float As[32][132];
    __shared__ float Vs[32][64];
    const int tid = threadIdx.x;
    const int tx = tid & 15, ty = tid >> 4;
    const int row0 = blockIdx.x * 128;
    const int bh = blockIdx.y;
    float* ab = attn + (size_t)bh * NS * NS;
    const float* vb = v + (size_t)bh * NS * NDK;
    const int sr = tid >> 3;
    const int sc = tid & 7;

    float Mr[4], iL[4];
#pragma unroll
    for (int i = 0; i < 4; ++i) {
        Mr[i] = Mrow[(size_t)bh * NS + row0 + sr + 32 * i];
        iL[i] = iLrow[(size_t)bh * NS + row0 + sr + 32 * i];
    }

    float acc[8][4] = {};

    for (int k0 = 0; k0 < NS; k0 += 32) {
#pragma unroll
        for (int i = 0; i < 4; ++i) {
            int r = sr + 32 * i;
            size_t off = (size_t)(row0 + r) * NS + k0 + sc * 4;
            float4 a = *(const float4*)&ab[off];
            a.x = expf(a.x - Mr[i]) * iL[i];
            a.y = expf(a.y - Mr[i]) * iL[i];
            a.z = expf(a.z - Mr[i]) * iL[i];
            a.w = expf(a.w - Mr[i]) * iL[i];
            *(float4*)&ab[off] = a;
            As[sc*4+0][r]=a.x; As[sc*4+1][r]=a.y; As[sc*4+2][r]=a.z; As[sc*4+3][r]=a.w;
        }
        {
            int vr = tid >> 4, cg = tid & 15;
#pragma unroll
            for (int i = 0; i < 2; ++i) {
                float4 b = *(const float4*)&vb[(size_t)(k0 + vr + 16 * i) * NDK + cg * 4];
                *(float4*)&Vs[vr + 16 * i][cg * 4] = b;
            }
        }
        __syncthreads();
#pragma unroll
        for (int kk = 0; kk < 32; ++kk) {
            float a[8], b[4];
#pragma unroll
            for (int i = 0; i < 8; ++i) a[i] = As[kk][ty * 8 + i];
#pragma unroll
            for (int j = 0; j < 4; ++j) b[j] = Vs[kk][tx * 4 + j];
#pragma unroll
            for (int i = 0; i < 8; ++i)
#pragma unroll
                for (int j = 0; j < 4; ++j)
                    acc[i][j] += a[i] * b[j];
        }
        __syncthreads();
    }

    const int b_ = bh >> 3, h_ = bh & 7;
#pragma unroll
    for (int i = 0; i < 8; ++i) {
        int r = row0 + ty * 8 + i;
        float4 o = { acc[i][0], acc[i][1], acc[i][2], acc[i][3] };
        *(float4*)&ctx[((size_t)b_ * NS + r) * ND + h_ * NDK + tx * 4] = o;
    }
}

// ---------------------------------------------------------------------------
// out[r][c] = sum_k ctx[r][k] * Wo[c][k] + bo[c] + residual[r][c]
// ---------------------------------------------------------------------------
__global__ __launch_bounds__(256) void k_outproj(
    const float* __restrict__ Xc, const float* __restrict__ W,
    const float* __restrict__ bias, const float* __restrict__ Qin,
    float* __restrict__ out)
{
    __shared__ float As[32][132];
    __shared__ float Bs[32][132];
    const int tid = threadIdx.x;
    const int tx = tid & 15, ty = tid >> 4;
    const int row0 = blockIdx.y * 128;
    const int col0 = blockIdx.x * 128;
    const int sr = tid >> 3;
    const int sc = tid & 7;

    float acc[8][8] = {};

    for (int k0 = 0; k0 < ND; k0 += 32) {
#pragma unroll
        for (int i = 0; i < 4; ++i) {
            int r = sr + 32 * i;
            float4 a = *(const float4*)&Xc[(size_t)(row0 + r) * ND + k0 + sc * 4];
            As[sc*4+0][r]=a.x; As[sc*4+1][r]=a.y; As[sc*4+2][r]=a.z; As[sc*4+3][r]=a.w;
            float4 b = *(const float4*)&W[(size_t)(col0 + r) * ND + k0 + sc * 4];
            Bs[sc*4+0][r]=b.x; Bs[sc*4+1][r]=b.y; Bs[sc*4+2][r]=b.z; Bs[sc*4+3][r]=b.w;
        }
        __syncthreads();
#pragma unroll
        for (int kk = 0; kk < 32; ++kk) {
            float a[8], b[8];
#pragma unroll
            for (int i = 0; i < 8; ++i) a[i] = As[kk][ty * 8 + i];
#pragma unroll
            for (int j = 0; j < 8; ++j) b[j] = Bs[kk][tx * 8 + j];
#pragma unroll
            for (int i = 0; i < 8; ++i)
#pragma unroll
                for (int j = 0; j < 8; ++j)
                    acc[i][j] += a[i] * b[j];
        }
        __syncthreads();
    }

#pragma unroll
    for (int i = 0; i < 8; ++i) {
        int r = row0 + ty * 8 + i;
#pragma unroll
        for (int jj = 0; jj < 2; ++jj) {
            int c = col0 + tx * 8 + jj * 4;
            float4 res = *(const float4*)&Qin[(size_t)r * ND + c];
            float4 o;
            o.x = acc[i][jj*4+0] + bias[c+0] + res.x;
            o.y = acc[i][jj*4+1] + bias[c+1] + res.y;
            o.z = acc[i][jj*4+2] + bias[c+2] + res.z;
            o.w = acc[i][jj*4+3] + bias[c+3] + res.w;
            *(float4*)&out[(size_t)r * ND + c] = o;
        }
    }
}

// ---------------------------------------------------------------------------
// In-place LayerNorm over last dim (512). One block per row, 2 f32/thread.
// ---------------------------------------------------------------------------
__global__ __launch_bounds__(256) void k_ln(
    float* __restrict__ out, const float* __restrict__ gamma,
    const float* __restrict__ beta)
{
    const int tid = threadIdx.x;
    float* p = out + (size_t)blockIdx.x * ND;
    float2 v = *(const float2*)&p[tid * 2];

    float s = v.x + v.y;
#pragma unroll
    for (int off = 32; off > 0; off >>= 1) s += __shfl_xor(s, off);
    __shared__ float red1[4];
    __shared__ float red2[4];
    if ((tid & 63) == 0) red1[tid >> 6] = s;
    __syncthreads();
    const float mu = (red1[0] + red1[1] + red1[2] + red1[3]) * (1.0f / ND);

    float dx = v.x - mu, dy = v.y - mu;
    float q = dx * dx + dy * dy;
#pragma unroll
    for (int off = 32; off > 0; off >>= 1) q += __shfl_xor(q, off);
    if ((tid & 63) == 0) red2[tid >> 6] = q;
    __syncthreads();
    const float var = (red2[0] + red2[1] + red2[2] + red2[3]) * (1.0f / ND);
    const float inv = rsqrtf(var + LN_EPS);

    float2 g = *(const float2*)&gamma[tid * 2];
    float2 be = *(const float2*)&beta[tid * 2];
    float2 o = { dx * inv * g.x + be.x, dy * inv * g.y + be.y };
    *(float2*)&p[tid * 2] = o;
}

// ---------------------------------------------------------------------------
extern "C" void kernel_launch(void* const* d_in, const int* in_sizes, int n_in,
                              void* d_out, int out_size, void* d_ws, size_t ws_size,
                              hipStream_t stream)
{
    const float* Q    = (const float*)d_in[0];
    const float* K    = (const float*)d_in[1];
    const float* V    = (const float*)d_in[2];
    const float* Wq   = (const float*)d_in[3];
    const float* bq   = (const float*)d_in[4];
    const float* Wk   = (const float*)d_in[5];
    const float* bk   = (const float*)d_in[6];
    const float* Wv   = (const float*)d_in[7];
    const float* bv   = (const float*)d_in[8];
    const float* Wo   = (const float*)d_in[9];
    const float* bo   = (const float*)d_in[10];
    const float* gam  = (const float*)d_in[11];
    const float* bet  = (const float*)d_in[12];

    float* out  = (float*)d_out;                       // [NB*NS*ND]
    float* attn = out + (size_t)NB * NS * ND;          // [NB*NH*NS*NS]

    const size_t qkv_elems = (size_t)NB * NH * NS * NDK;   // 4 Mi
    float* qw    = (float*)d_ws;
    float* kw    = qw + qkv_elems;
    float* vw    = kw + qkv_elems;
    float* mpart = vw + qkv_elems;                     // [32][16][2048]
    float* lpart = mpart + (size_t)32 * 16 * NS;
    float* Mrow  = lpart + (size_t)32 * 16 * NS;       // [32][2048]
    float* iLrow = Mrow + (size_t)32 * NS;
    float* ctx   = qw;   // q dead after k_scores; reuse for context

    dim3 blk(256);

    dim3 gProj(ND / 128, (NB * NS) / 128);             // (4, 64)
    k_proj<<<gProj, blk, 0, stream>>>(Q, Wq, bq, qw);
    k_proj<<<gProj, blk, 0, stream>>>(K, Wk, bk, kw);
    k_proj<<<gProj, blk, 0, stream>>>(V, Wv, bv, vw);

    dim3 gSc(NS / 128, NS / 128, NB * NH);             // (16, 16, 32)
    k_scores<<<gSc, blk, 0, stream>>>(qw, kw, attn, mpart, lpart);

    k_redstats<<<dim3((NB * NH * NS) / 256), blk, 0, stream>>>(mpart, lpart, Mrow, iLrow);

    dim3 gCtx(NS / 128, NB * NH);                      // (16, 32)
    k_ctx<<<gCtx, blk, 0, stream>>>(vw, attn, Mrow, iLrow, ctx);

    dim3 gOut(ND / 128, (NB * NS) / 128);              // (4, 64)
    k_outproj<<<gOut, blk, 0, stream>>>(ctx, Wo, bo, Q, out);

    k_ln<<<dim3(NB * NS), blk, 0, stream>>>(out, gam, bet);
}

// Round 3
// 830.229 us; speedup vs baseline: 1.2542x; 1.1970x over previous
//
#include <hip/hip_runtime.h>

#define NB 4
#define NS 2048
#define ND 512
#define NH 8
#define NDK 64
#define LN_EPS 1e-5f

typedef __attribute__((ext_vector_type(8))) short short8;
typedef __attribute__((ext_vector_type(4))) float f32x4;

__device__ inline short f2bf(float x) {
    unsigned u = __builtin_bit_cast(unsigned, x);
    unsigned r = (u + 0x7FFFu + ((u >> 16) & 1u)) >> 16;
    return (short)r;
}
__device__ inline float bf2f(short h) {
    unsigned u = ((unsigned)(unsigned short)h) << 16;
    return __builtin_bit_cast(float, u);
}

// ---------------------------------------------------------------------------
// Projection GEMM core (f32, 128x128 tile, BK=32, 8x8 micro).
// MODE 0: write bf16 hi+lo in [B,H,S,DK] layout (for Q,K -> MFMA frags)
// MODE 1: write bf16 V-transposed [B,H,DK,S] (for PV B-frags)
// ---------------------------------------------------------------------------
template<int MODE>
__global__ __launch_bounds__(256) void k_proj_t(
    const float* __restrict__ X, const float* __restrict__ W,
    const float* __restrict__ bias,
    short* __restrict__ outh, short* __restrict__ outl)
{
    __shared__ float As[32][132];
    __shared__ float Bs[32][132];
    const int tid = threadIdx.x;
    const int tx = tid & 15, ty = tid >> 4;
    const int row0 = blockIdx.y * 128;
    const int col0 = blockIdx.x * 128;
    const int sr = tid >> 3;
    const int sc = tid & 7;

    float acc[8][8] = {};

    for (int k0 = 0; k0 < ND; k0 += 32) {
#pragma unroll
        for (int i = 0; i < 4; ++i) {
            int r = sr + 32 * i;
            float4 a = *(const float4*)&X[(size_t)(row0 + r) * ND + k0 + sc * 4];
            As[sc*4+0][r]=a.x; As[sc*4+1][r]=a.y; As[sc*4+2][r]=a.z; As[sc*4+3][r]=a.w;
            float4 b = *(const float4*)&W[(size_t)(col0 + r) * ND + k0 + sc * 4];
            Bs[sc*4+0][r]=b.x; Bs[sc*4+1][r]=b.y; Bs[sc*4+2][r]=b.z; Bs[sc*4+3][r]=b.w;
        }
        __syncthreads();
#pragma unroll
        for (int kk = 0; kk < 32; ++kk) {
            float a[8], b[8];
#pragma unroll
            for (int i = 0; i < 8; ++i) a[i] = As[kk][ty * 8 + i];
#pragma unroll
            for (int j = 0; j < 8; ++j) b[j] = Bs[kk][tx * 8 + j];
#pragma unroll
            for (int i = 0; i < 8; ++i)
#pragma unroll
                for (int j = 0; j < 8; ++j)
                    acc[i][j] += a[i] * b[j];
        }
        __syncthreads();
    }

    if (MODE == 0) {
#pragma unroll
        for (int i = 0; i < 8; ++i) {
            int r = row0 + ty * 8 + i;
            int b_ = r >> 11, s_ = r & (NS - 1);
            int c0 = col0 + tx * 8;
            int h_ = c0 >> 6, dk = c0 & (NDK - 1);
            short8 hh, ll;
#pragma unroll
            for (int j = 0; j < 8; ++j) {
                float x = acc[i][j] + bias[c0 + j];
                short hb = f2bf(x);
                hh[j] = hb;
                ll[j] = f2bf(x - bf2f(hb));
            }
            size_t idx = (((size_t)b_ * NH + h_) * NS + s_) * NDK + dk;
            *(short8*)&outh[idx] = hh;
            *(short8*)&outl[idx] = ll;
        }
    } else {
        int r0 = row0 + ty * 8;
        int b_ = r0 >> 11, s0 = r0 & (NS - 1);
#pragma unroll
        for (int j = 0; j < 8; ++j) {
            int c = col0 + tx * 8 + j;
            int h_ = c >> 6, dk = c & (NDK - 1);
            short8 vv;
#pragma unroll
            for (int i = 0; i < 8; ++i) vv[i] = f2bf(acc[i][j] + bias[c]);
            *(short8*)&outh[(((size_t)b_ * NH + h_) * NDK + dk) * NS + s0] = vv;
        }
    }
}

// ---------------------------------------------------------------------------
// QK^T via split-bf16 MFMA (hi*hi + hi*lo + lo*hi ~= f32 accuracy).
// 128x128 tile / 4 waves; wave w owns rows [w*32, w*32+32).
// Writes raw f32 scores to attn + per-(row,128-colblock) partial stats.
// ---------------------------------------------------------------------------
__global__ __launch_bounds__(256) void k_scores_mfma(
    const short* __restrict__ qh, const short* __restrict__ ql,
    const short* __restrict__ kh, const short* __restrict__ kl,
    float* __restrict__ attn, float* __restrict__ mpart,
    float* __restrict__ lpart)
{
    const int tid = threadIdx.x;
    const int w = tid >> 6, lane = tid & 63;
    const int lr = lane & 15, lg = lane >> 4;
    const int bh = blockIdx.z;
    const int row0 = blockIdx.y * 128 + w * 32;
    const int col0 = blockIdx.x * 128;
    const size_t qbase = (size_t)bh * NS * NDK;

    short8 ah[2][2], al[2][2];
#pragma unroll
    for (int rs = 0; rs < 2; ++rs)
#pragma unroll
        for (int ks = 0; ks < 2; ++ks) {
            size_t idx = qbase + (size_t)(row0 + rs * 16 + lr) * NDK + ks * 32 + lg * 8;
            ah[rs][ks] = *(const short8*)&qh[idx];
            al[rs][ks] = *(const short8*)&ql[idx];
        }

    f32x4 acc[2][8] = {};
#pragma unroll
    for (int cs = 0; cs < 8; ++cs) {
        short8 bhf[2], blf[2];
#pragma unroll
        for (int ks = 0; ks < 2; ++ks) {
            size_t idx = qbase + (size_t)(col0 + cs * 16 + lr) * NDK + ks * 32 + lg * 8;
            bhf[ks] = *(const short8*)&kh[idx];
            blf[ks] = *(const short8*)&kl[idx];
        }
#pragma unroll
        for (int rs = 0; rs < 2; ++rs)
#pragma unroll
            for (int ks = 0; ks < 2; ++ks) {
                acc[rs][cs] = __builtin_amdgcn_mfma_f32_16x16x32_bf16(ah[rs][ks], bhf[ks], acc[rs][cs], 0, 0, 0);
                acc[rs][cs] = __builtin_amdgcn_mfma_f32_16x16x32_bf16(ah[rs][ks], blf[ks], acc[rs][cs], 0, 0, 0);
                acc[rs][cs] = __builtin_amdgcn_mfma_f32_16x16x32_bf16(al[rs][ks], bhf[ks], acc[rs][cs], 0, 0, 0);
            }
    }

    float* ab = attn + (size_t)bh * NS * NS;
    const size_t statbase = ((size_t)bh * 16 + blockIdx.x) * NS;
#pragma unroll
    for (int rs = 0; rs < 2; ++rs)
#pragma unroll
        for (int r = 0; r < 4; ++r) {
            const int row = row0 + rs * 16 + lg * 4 + r;
            float m = -3.4e38f;
#pragma unroll
            for (int cs = 0; cs < 8; ++cs) m = fmaxf(m, acc[rs][cs][r]);
#pragma unroll
            for (int off = 1; off < 16; off <<= 1) m = fmaxf(m, __shfl_xor(m, off));
            float l = 0.f;
#pragma unroll
            for (int cs = 0; cs < 8; ++cs) l += __expf(acc[rs][cs][r] - m);
#pragma unroll
            for (int off = 1; off < 16; off <<= 1) l += __shfl_xor(l, off);
#pragma unroll
            for (int cs = 0; cs < 8; ++cs)
                ab[(size_t)row * NS + col0 + cs * 16 + lr] = acc[rs][cs][r];
            if (lr == 0) { mpart[statbase + row] = m; lpart[statbase + row] = l; }
        }
}

// ---------------------------------------------------------------------------
// Combine 16 col-block partials per row -> global max M and 1/L.
// ---------------------------------------------------------------------------
__global__ __launch_bounds__(256) void k_redstats(
    const float* __restrict__ mpart, const float* __restrict__ lpart,
    float* __restrict__ Mrow, float* __restrict__ iLrow)
{
    const int idx = blockIdx.x * 256 + threadIdx.x;
    const int bh = idx >> 11, r = idx & (NS - 1);
    const float* mp = mpart + (size_t)bh * 16 * NS + r;
    const float* lp = lpart + (size_t)bh * 16 * NS + r;
    float M = -3.4e38f;
#pragma unroll
    for (int c = 0; c < 16; ++c) M = fmaxf(M, mp[(size_t)c * NS]);
    float L = 0.f;
#pragma unroll
    for (int c = 0; c < 16; ++c) L += lp[(size_t)c * NS] * __expf(mp[(size_t)c * NS] - M);
    Mrow[idx] = M;
    iLrow[idx] = 1.0f / L;
}

// ---------------------------------------------------------------------------
// Normalize + PV via MFMA. 64-row tiles, 4 waves x 16 rows, full DK=64.
// Lane (lr,lg) streams row lr's raw scores, p = exp(s-M)*iL, writes p back
// (final attn output) and feeds bf16 A-frags; B-frags from bf16 V^T.
// ---------------------------------------------------------------------------
__global__ __launch_bounds__(256) void k_ctx_mfma(
    float* __restrict__ attn, const short* __restrict__ vtb,
    const float* __restrict__ Mrow, const float* __restrict__ iLrow,
    float* __restrict__ ctx)
{
    const int tid = threadIdx.x;
    const int w = tid >> 6, lane = tid & 63;
    const int lr = lane & 15, lg = lane >> 4;
    const int bh = blockIdx.y;
    const int row0 = blockIdx.x * 64 + w * 16;
    const int myrow = row0 + lr;
    float* ab = attn + ((size_t)bh * NS + myrow) * NS;
    const float M = Mrow[(size_t)bh * NS + myrow];
    const float iL = iLrow[(size_t)bh * NS + myrow];
    const short* vb = vtb + (size_t)bh * NDK * NS;

    f32x4 acc[4] = {};
#pragma unroll 2
    for (int k0 = 0; k0 < NS; k0 += 32) {
        const int kof = k0 + lg * 8;
        float4 s0 = *(const float4*)&ab[kof];
        float4 s1 = *(const float4*)&ab[kof + 4];
        float p[8];
        p[0] = __expf(s0.x - M) * iL; p[1] = __expf(s0.y - M) * iL;
        p[2] = __expf(s0.z - M) * iL; p[3] = __expf(s0.w - M) * iL;
        p[4] = __expf(s1.x - M) * iL; p[5] = __expf(s1.y - M) * iL;
        p[6] = __expf(s1.z - M) * iL; p[7] = __expf(s1.w - M) * iL;
        float4 o0 = { p[0], p[1], p[2], p[3] };
        float4 o1 = { p[4], p[5], p[6], p[7] };
        *(float4*)&ab[kof] = o0;
        *(float4*)&ab[kof + 4] = o1;
        short8 af;
#pragma unroll
        for (int j = 0; j < 8; ++j) af[j] = f2bf(p[j]);
#pragma unroll
        for (int cs = 0; cs < 4; ++cs) {
            short8 vf = *(const short8*)&vb[(size_t)(cs * 16 + lr) * NS + kof];
            acc[cs] = __builtin_amdgcn_mfma_f32_16x16x32_bf16(af, vf, acc[cs], 0, 0, 0);
        }
    }

    const int b_ = bh >> 3, h_ = bh & 7;
#pragma unroll
    for (int cs = 0; cs < 4; ++cs)
#pragma unroll
        for (int r = 0; r < 4; ++r) {
            int row = row0 + lg * 4 + r;
            ctx[((size_t)b_ * NS + row) * ND + h_ * NDK + cs * 16 + lr] = acc[cs][r];
        }
}

// ---------------------------------------------------------------------------
// out[r][c] = sum_k ctx[r][k] * Wo[c][k] + bo[c] + residual[r][c]
// ---------------------------------------------------------------------------
__global__ __launch_bounds__(256) void k_outproj(
    const float* __restrict__ Xc, const float* __restrict__ W,
    const float* __restrict__ bias, const float* __restrict__ Qin,
    float* __restrict__ out)
{
    __shared__ float As[32][132];
    __shared__ float Bs[32][132];
    const int tid = threadIdx.x;
    const int tx = tid & 15, ty = tid >> 4;
    const int row0 = blockIdx.y * 128;
    const int col0 = blockIdx.x * 128;
    const int sr = tid >> 3;
    const int sc = tid & 7;

    float acc[8][8] = {};

    for (int k0 = 0; k0 < ND; k0 += 32) {
#pragma unroll
        for (int i = 0; i < 4; ++i) {
            int r = sr + 32 * i;
            float4 a = *(const float4*)&Xc[(size_t)(row0 + r) * ND + k0 + sc * 4];
            As[sc*4+0][r]=a.x; As[sc*4+1][r]=a.y; As[sc*4+2][r]=a.z; As[sc*4+3][r]=a.w;
            float4 b = *(const float4*)&W[(size_t)(col0 + r) * ND + k0 + sc * 4];
            Bs[sc*4+0][r]=b.x; Bs[sc*4+1][r]=b.y; Bs[sc*4+2][r]=b.z; Bs[sc*4+3][r]=b.w;
        }
        __syncthreads();
#pragma unroll
        for (int kk = 0; kk < 32; ++kk) {
            float a[8], b[8];
#pragma unroll
            for (int i = 0; i < 8; ++i) a[i] = As[kk][ty * 8 + i];
#pragma unroll
            for (int j = 0; j < 8; ++j) b[j] = Bs[kk][tx * 8 + j];
#pragma unroll
            for (int i = 0; i < 8; ++i)
#pragma unroll
                for (int j = 0; j < 8; ++j)
                    acc[i][j] += a[i] * b[j];
        }
        __syncthreads();
    }

#pragma unroll
    for (int i = 0; i < 8; ++i) {
        int r = row0 + ty * 8 + i;
#pragma unroll
        for (int jj = 0; jj < 2; ++jj) {
            int c = col0 + tx * 8 + jj * 4;
            float4 res = *(const float4*)&Qin[(size_t)r * ND + c];
            float4 o;
            o.x = acc[i][jj*4+0] + bias[c+0] + res.x;
            o.y = acc[i][jj*4+1] + bias[c+1] + res.y;
            o.z = acc[i][jj*4+2] + bias[c+2] + res.z;
            o.w = acc[i][jj*4+3] + bias[c+3] + res.w;
            *(float4*)&out[(size_t)r * ND + c] = o;
        }
    }
}

// ---------------------------------------------------------------------------
// In-place LayerNorm over last dim (512).
// ---------------------------------------------------------------------------
__global__ __launch_bounds__(256) void k_ln(
    float* __restrict__ out, const float* __restrict__ gamma,
    const float* __restrict__ beta)
{
    const int tid = threadIdx.x;
    float* p = out + (size_t)blockIdx.x * ND;
    float2 v = *(const float2*)&p[tid * 2];

    float s = v.x + v.y;
#pragma unroll
    for (int off = 32; off > 0; off >>= 1) s += __shfl_xor(s, off);
    __shared__ float red1[4];
    __shared__ float red2[4];
    if ((tid & 63) == 0) red1[tid >> 6] = s;
    __syncthreads();
    const float mu = (red1[0] + red1[1] + red1[2] + red1[3]) * (1.0f / ND);

    float dx = v.x - mu, dy = v.y - mu;
    float q = dx * dx + dy * dy;
#pragma unroll
    for (int off = 32; off > 0; off >>= 1) q += __shfl_xor(q, off);
    if ((tid & 63) == 0) red2[tid >> 6] = q;
    __syncthreads();
    const float var = (red2[0] + red2[1] + red2[2] + red2[3]) * (1.0f / ND);
    const float inv = rsqrtf(var + LN_EPS);

    float2 g = *(const float2*)&gamma[tid * 2];
    float2 be = *(const float2*)&beta[tid * 2];
    float2 o = { dx * inv * g.x + be.x, dy * inv * g.y + be.y };
    *(float2*)&p[tid * 2] = o;
}

// ---------------------------------------------------------------------------
extern "C" void kernel_launch(void* const* d_in, const int* in_sizes, int n_in,
                              void* d_out, int out_size, void* d_ws, size_t ws_size,
                              hipStream_t stream)
{
    const float* Q    = (const float*)d_in[0];
    const float* K    = (const float*)d_in[1];
    const float* V    = (const float*)d_in[2];
    const float* Wq   = (const float*)d_in[3];
    const float* bq   = (const float*)d_in[4];
    const float* Wk   = (const float*)d_in[5];
    const float* bk   = (const float*)d_in[6];
    const float* Wv   = (const float*)d_in[7];
    const float* bv   = (const float*)d_in[8];
    const float* Wo   = (const float*)d_in[9];
    const float* bo   = (const float*)d_in[10];
    const float* gam  = (const float*)d_in[11];
    const float* bet  = (const float*)d_in[12];

    float* out  = (float*)d_out;                       // [NB*NS*ND]
    float* attn = out + (size_t)NB * NS * ND;          // [NB*NH*NS*NS]

    const size_t QKV = (size_t)NB * NH * NS * NDK;     // 4.19M elements
    short* qh  = (short*)d_ws;
    short* ql  = qh + QKV;
    short* kh  = ql + QKV;
    short* kl  = kh + QKV;
    short* vtb = kl + QKV;
    float* mpart = (float*)(vtb + QKV);                // [32][16][2048]
    float* lpart = mpart + (size_t)32 * 16 * NS;
    float* Mrow  = lpart + (size_t)32 * 16 * NS;       // [32][2048]
    float* iLrow = Mrow + (size_t)32 * NS;
    float* ctx   = (float*)qh;   // overlay: qh/ql dead after k_scores

    dim3 blk(256);

    dim3 gProj(ND / 128, (NB * NS) / 128);             // (4, 64)
    k_proj_t<0><<<gProj, blk, 0, stream>>>(Q, Wq, bq, qh, ql);
    k_proj_t<0><<<gProj, blk, 0, stream>>>(K, Wk, bk, kh, kl);
    k_proj_t<1><<<gProj, blk, 0, stream>>>(V, Wv, bv, vtb, (short*)nullptr);

    dim3 gSc(NS / 128, NS / 128, NB * NH);             // (16, 16, 32)
    k_scores_mfma<<<gSc, blk, 0, stream>>>(qh, ql, kh, kl, attn, mpart, lpart);

    k_redstats<<<dim3((NB * NH * NS) / 256), blk, 0, stream>>>(mpart, lpart, Mrow, iLrow);

    dim3 gCtx(NS / 64, NB * NH);                       // (32, 32)
    k_ctx_mfma<<<gCtx, blk, 0, stream>>>(attn, vtb, Mrow, iLrow, ctx);

    dim3 gOut(ND / 128, (NB * NS) / 128);              // (4, 64)
    k_outproj<<<gOut, blk, 0, stream>>>(ctx, Wo, bo, Q, out);

    k_ln<<<dim3(NB * NS), blk, 0, stream>>>(out, gam, bet);
}